// Round 6
// baseline (637.281 us; speedup 1.0000x reference)
//
#include <hip/hip_runtime.h>

#define NN 50000
#define NE 800000
#define SCAN_BLOCKS 196   // 196*256 = 50176 >= NN

typedef __attribute__((ext_vector_type(8))) short short8;
typedef __attribute__((ext_vector_type(4))) float float4v;

struct us4 { unsigned short x, y, z, w; };
struct us8 { unsigned short v[8]; };

__device__ __forceinline__ unsigned short f2bf(float f) {
    unsigned u = __float_as_uint(f);
    unsigned r = (u + 0x7FFF + ((u >> 16) & 1)) >> 16;   // RNE
    return (unsigned short)r;
}

__device__ __forceinline__ float bf2f(unsigned short u) {
    return __uint_as_float((unsigned)u << 16);
}

__device__ __forceinline__ void gload_lds16(const unsigned short* g, unsigned short* l) {
    __builtin_amdgcn_global_load_lds(
        (const __attribute__((address_space(1))) unsigned int*)g,
        (__attribute__((address_space(3))) unsigned int*)l,
        16, 0, 0);
}

// ---------------- bf16 MFMA GEMM: C[N,M] = A[N,K] @ Bt[M,K]^T ----------------
// AFP32=1: A is fp32, staged via VGPR + convert (fuses the x->bf16 pass).
template <int BM, int BN, int WM, int WN, int OUTBF, int AFP32>
__global__ __launch_bounds__(256) void gemm_mfma(const void* __restrict__ Av,
                                                 const unsigned short* __restrict__ Bt,
                                                 void* __restrict__ Cv,
                                                 int N, int K, int M) {
    constexpr int BK = 32;
    constexpr int MT = WM / 16;
    constexpr int NT = WN / 16;
    constexpr int WCOLS = BN / WN;

    __shared__ __align__(16) unsigned short As[BM * BK];
    __shared__ __align__(16) unsigned short Bs[BN * BK];

    const int tid = threadIdx.x;
    const int lane = tid & 63;
    const int wid = tid >> 6;
    const int col16 = lane & 15;
    const int q = lane >> 4;
    const int wr = (wid / WCOLS) * WM;
    const int wc = (wid % WCOLS) * WN;
    const int rowBase = blockIdx.y * BM;
    const int colBase = blockIdx.x * BN;

    const int srow = lane >> 2;
    const int scol = (lane & 3) * 8;

    float4v acc[MT][NT];
#pragma unroll
    for (int t = 0; t < MT; ++t)
#pragma unroll
        for (int u = 0; u < NT; ++u)
            acc[t][u] = (float4v)0.f;

    for (int k0 = 0; k0 < K; k0 += BK) {
        __syncthreads();
        // stage A
#pragma unroll
        for (int l = wid; l < BM / 16; l += 4) {
            int row = rowBase + 16 * l + srow;
            row = row < N ? row : N - 1;
            if (AFP32) {
                const float* Af = (const float*)Av;
                const float4* p = (const float4*)(Af + (size_t)row * K + k0 + scol);
                const float4 v0 = p[0];
                const float4 v1 = p[1];
                short8 o;
                o[0] = (short)f2bf(v0.x); o[1] = (short)f2bf(v0.y);
                o[2] = (short)f2bf(v0.z); o[3] = (short)f2bf(v0.w);
                o[4] = (short)f2bf(v1.x); o[5] = (short)f2bf(v1.y);
                o[6] = (short)f2bf(v1.z); o[7] = (short)f2bf(v1.w);
                *(short8*)&As[l * 512 + lane * 8] = o;   // ds_write_b128
            } else {
                const unsigned short* Ab = (const unsigned short*)Av;
                gload_lds16(Ab + (size_t)row * K + k0 + scol, &As[l * 512]);
            }
        }
        // stage B
#pragma unroll
        for (int l = wid; l < BN / 16; l += 4) {
            const int row = colBase + 16 * l + srow;
            gload_lds16(Bt + (size_t)row * K + k0 + scol, &Bs[l * 512]);
        }
        __syncthreads();

        short8 a[MT], b[NT];
#pragma unroll
        for (int t = 0; t < MT; ++t)
            a[t] = *(const short8*)&As[(wr + t * 16 + col16) * BK + q * 8];
#pragma unroll
        for (int u = 0; u < NT; ++u)
            b[u] = *(const short8*)&Bs[(wc + u * 16 + col16) * BK + q * 8];
#pragma unroll
        for (int t = 0; t < MT; ++t)
#pragma unroll
            for (int u = 0; u < NT; ++u)
                acc[t][u] = __builtin_amdgcn_mfma_f32_16x16x32_bf16(a[t], b[u], acc[t][u], 0, 0, 0);
    }

    // epilogue: C/D layout col=lane&15, row=q*4+reg
#pragma unroll
    for (int t = 0; t < MT; ++t) {
        const int row0 = rowBase + wr + t * 16 + q * 4;
#pragma unroll
        for (int u = 0; u < NT; ++u) {
            const int col = colBase + wc + u * 16 + col16;
#pragma unroll
            for (int r = 0; r < 4; ++r) {
                const int row = row0 + r;
                if (row < N) {
                    if (OUTBF)
                        ((unsigned short*)Cv)[(size_t)row * M + col] = f2bf(acc[t][u][r]);
                    else
                        ((float*)Cv)[(size_t)row * M + col] = acc[t][u][r];
                }
            }
        }
    }
}

// ---------------- conversions ----------------
__global__ void cvt_transpose(const float* __restrict__ W, unsigned short* __restrict__ Wt,
                              int K, int M) {
    int idx = blockIdx.x * blockDim.x + threadIdx.x;
    const int total = K * M;
    if (idx < total) {
        const int k = idx / M;
        const int m = idx % M;
        Wt[(size_t)m * K + k] = f2bf(W[idx]);
    }
}

// ---------------- CSR build ----------------
__global__ void zero_counts(int* __restrict__ counts) {
    int i = blockIdx.x * blockDim.x + threadIdx.x;
    if (i < NN) counts[i] = 0;
}

__global__ void hist_dst(const int* __restrict__ dst, int* __restrict__ counts) {
    int i = blockIdx.x * blockDim.x + threadIdx.x;
    const int stride = gridDim.x * blockDim.x;
    for (; i < NE; i += stride) atomicAdd(&counts[dst[i]], 1);
}

__global__ __launch_bounds__(256) void scan_partial(const int* __restrict__ counts,
                                                    int* __restrict__ partials) {
    __shared__ int r[256];
    const int t = threadIdx.x;
    const int i = blockIdx.x * 256 + t;
    r[t] = (i < NN) ? counts[i] : 0;
    __syncthreads();
    for (int s = 128; s > 0; s >>= 1) {
        if (t < s) r[t] += r[t + s];
        __syncthreads();
    }
    if (t == 0) partials[blockIdx.x] = r[0];
}

__global__ __launch_bounds__(256) void scan_base(const int* __restrict__ partials,
                                                 int* __restrict__ bases,
                                                 int* __restrict__ offs) {
    __shared__ int s[256];
    const int t = threadIdx.x;
    const int v = (t < SCAN_BLOCKS) ? partials[t] : 0;
    s[t] = v;
    __syncthreads();
    for (int off = 1; off < 256; off <<= 1) {
        int x = (t >= off) ? s[t - off] : 0;
        __syncthreads();
        s[t] += x;
        __syncthreads();
    }
    if (t < SCAN_BLOCKS) bases[t] = s[t] - v;
    if (t == 255) offs[NN] = s[255];
}

__global__ __launch_bounds__(256) void scan_final(int* __restrict__ counts,
                                                  const int* __restrict__ bases,
                                                  int* __restrict__ offs) {
    __shared__ int s[256];
    const int t = threadIdx.x;
    const int i = blockIdx.x * 256 + t;
    const int v = (i < NN) ? counts[i] : 0;
    s[t] = v;
    __syncthreads();
    for (int off = 1; off < 256; off <<= 1) {
        int x = (t >= off) ? s[t - off] : 0;
        __syncthreads();
        s[t] += x;
        __syncthreads();
    }
    if (i < NN) {
        const int e = bases[blockIdx.x] + s[t] - v;
        offs[i] = e;
        counts[i] = e;
    }
}

__global__ void fill_csr(const int* __restrict__ src, const int* __restrict__ dst,
                         const float* __restrict__ w, int* __restrict__ cursor,
                         int* __restrict__ csr_src, float* __restrict__ csr_w) {
    int i = blockIdx.x * blockDim.x + threadIdx.x;
    const int stride = gridDim.x * blockDim.x;
    for (; i < NE; i += stride) {
        const int p = atomicAdd(&cursor[dst[i]], 1);
        csr_src[p] = src[i];
        csr_w[p] = w[i];
    }
}

// ---------------- gather SpMM (bf16 h input), 4x edge unroll ----------------
template <int D, int RELU, int OUTBF>
__global__ __launch_bounds__(256) void spmm_gather(const int* __restrict__ offs,
                                                   const int* __restrict__ csr_src,
                                                   const float* __restrict__ csr_w,
                                                   const unsigned short* __restrict__ hp,
                                                   const float* __restrict__ bias,
                                                   void* __restrict__ outv) {
    constexpr int TPN = D / 8;
    constexpr int NPB = 256 / TPN;
    const int tid = threadIdx.x;
    const int node = blockIdx.x * NPB + tid / TPN;
    const int d = (tid % TPN) * 8;
    if (node >= NN) return;
    const int beg = offs[node];
    const int end = offs[node + 1];

    float acc[8] = {};
    int j = beg;
    for (; j + 4 <= end; j += 4) {
        const int s0 = csr_src[j];
        const int s1 = csr_src[j + 1];
        const int s2 = csr_src[j + 2];
        const int s3 = csr_src[j + 3];
        const float w0 = csr_w[j];
        const float w1 = csr_w[j + 1];
        const float w2 = csr_w[j + 2];
        const float w3 = csr_w[j + 3];
        const us8 h0 = *(const us8*)&hp[(long long)s0 * D + d];
        const us8 h1 = *(const us8*)&hp[(long long)s1 * D + d];
        const us8 h2 = *(const us8*)&hp[(long long)s2 * D + d];
        const us8 h3 = *(const us8*)&hp[(long long)s3 * D + d];
#pragma unroll
        for (int k = 0; k < 8; ++k)
            acc[k] += w0 * bf2f(h0.v[k]) + w1 * bf2f(h1.v[k])
                    + w2 * bf2f(h2.v[k]) + w3 * bf2f(h3.v[k]);
    }
    for (; j < end; ++j) {
        const int s0 = csr_src[j];
        const float w0 = csr_w[j];
        const us8 h0 = *(const us8*)&hp[(long long)s0 * D + d];
#pragma unroll
        for (int k = 0; k < 8; ++k)
            acc[k] += w0 * bf2f(h0.v[k]);
    }
#pragma unroll
    for (int k = 0; k < 8; ++k) {
        acc[k] += bias[d + k];
        if (RELU) acc[k] = fmaxf(acc[k], 0.f);
    }
    if (OUTBF) {
        us8 o;
#pragma unroll
        for (int k = 0; k < 8; ++k) o.v[k] = f2bf(acc[k]);
        *(us8*)((unsigned short*)outv + (long long)node * D + d) = o;
    } else {
        float* op = (float*)outv + (long long)node * D + d;
        *(float4*)op = make_float4(acc[0], acc[1], acc[2], acc[3]);
        *(float4*)(op + 4) = make_float4(acc[4], acc[5], acc[6], acc[7]);
    }
}

extern "C" void kernel_launch(void* const* d_in, const int* in_sizes, int n_in,
                              void* d_out, int out_size, void* d_ws, size_t ws_size,
                              hipStream_t stream) {
    const float* x    = (const float*)d_in[0];
    const int*   esrc = (const int*)d_in[1];
    const int*   edst = (const int*)d_in[2];
    const float* ew   = (const float*)d_in[3];
    const float* W1 = (const float*)d_in[4];  const float* b1 = (const float*)d_in[5];
    const float* W2 = (const float*)d_in[6];  const float* b2 = (const float*)d_in[7];
    const float* W3 = (const float*)d_in[8];  const float* b3 = (const float*)d_in[9];
    const float* W4 = (const float*)d_in[10]; const float* b4 = (const float*)d_in[11];
    float* out = (float*)d_out;

    // workspace layout
    char* ws = (char*)d_ws;
    int*   offs    = (int*)ws;                    ws += (NN + 1) * sizeof(int);
    int*   counts  = (int*)ws;                    ws += NN * sizeof(int);
    int*   partials= (int*)ws;                    ws += 256 * sizeof(int);
    int*   bases   = (int*)ws;                    ws += 256 * sizeof(int);
    int*   csr_src = (int*)ws;                    ws += NE * sizeof(int);
    float* csr_w   = (float*)ws;                  ws += NE * sizeof(float);
    unsigned short* Wt1 = (unsigned short*)ws;    ws += 512 * 512 * sizeof(unsigned short);
    unsigned short* Wt2 = (unsigned short*)ws;    ws += 256 * 512 * sizeof(unsigned short);
    unsigned short* Wt3 = (unsigned short*)ws;    ws += 128 * 256 * sizeof(unsigned short);
    unsigned short* Wt4 = (unsigned short*)ws;    ws += 64 * 128 * sizeof(unsigned short);
    ws = (char*)(((uintptr_t)ws + 255) & ~(uintptr_t)255);
    unsigned short* tmp = (unsigned short*)ws;    ws += (size_t)NN * 512 * sizeof(unsigned short);
    ws = (char*)(((uintptr_t)ws + 255) & ~(uintptr_t)255);
    unsigned short* hb = (unsigned short*)ws;     // N x 512 bf16; h1..h3

    // ---- CSR build ----
    zero_counts<<<(NN + 255) / 256, 256, 0, stream>>>(counts);
    hist_dst<<<3125, 256, 0, stream>>>(edst, counts);
    scan_partial<<<SCAN_BLOCKS, 256, 0, stream>>>(counts, partials);
    scan_base<<<1, 256, 0, stream>>>(partials, bases, offs);
    scan_final<<<SCAN_BLOCKS, 256, 0, stream>>>(counts, bases, offs);
    fill_csr<<<3125, 256, 0, stream>>>(esrc, edst, ew, counts, csr_src, csr_w);

    // ---- weight conversion ----
    cvt_transpose<<<(512 * 512 + 255) / 256, 256, 0, stream>>>(W1, Wt1, 512, 512);
    cvt_transpose<<<(512 * 256 + 255) / 256, 256, 0, stream>>>(W2, Wt2, 512, 256);
    cvt_transpose<<<(256 * 128 + 255) / 256, 256, 0, stream>>>(W3, Wt3, 256, 128);
    cvt_transpose<<<(128 * 64 + 255) / 256, 256, 0, stream>>>(W4, Wt4, 128, 64);

    const int nby128 = (NN + 127) / 128;   // 391
    const int nby64  = (NN + 63) / 64;     // 782

    // ---- layer 1: K=512, M=512 (A = x fp32, converted in-kernel) ----
    gemm_mfma<128, 128, 64, 64, 1, 1><<<dim3(4, nby128), 256, 0, stream>>>(x, Wt1, tmp, NN, 512, 512);
    spmm_gather<512, 1, 1><<<NN / 4, 256, 0, stream>>>(offs, csr_src, csr_w, tmp, b1, hb);
    // ---- layer 2: K=512, M=256 ----
    gemm_mfma<128, 128, 64, 64, 1, 0><<<dim3(2, nby128), 256, 0, stream>>>(hb, Wt2, tmp, NN, 512, 256);
    spmm_gather<256, 1, 1><<<NN / 8, 256, 0, stream>>>(offs, csr_src, csr_w, tmp, b2, hb);
    // ---- layer 3: K=256, M=128 (smaller BM for occupancy) ----
    gemm_mfma<64, 128, 32, 64, 1, 0><<<dim3(1, nby64), 256, 0, stream>>>(hb, Wt3, tmp, NN, 256, 128);
    spmm_gather<128, 1, 1><<<NN / 16, 256, 0, stream>>>(offs, csr_src, csr_w, tmp, b3, hb);
    // ---- layer 4: K=128, M=64 ----
    gemm_mfma<64, 64, 32, 32, 1, 0><<<dim3(1, nby64), 256, 0, stream>>>(hb, Wt4, tmp, NN, 128, 64);
    spmm_gather<64, 0, 0><<<(NN + 31) / 32, 256, 0, stream>>>(offs, csr_src, csr_w, tmp, b4, out);
}

// Round 7
// 609.586 us; speedup vs baseline: 1.0454x; 1.0454x over previous
//
#include <hip/hip_runtime.h>

#define NN 50000
#define NE 800000
#define SCAN_BLOCKS 196   // 196*256 = 50176 >= NN

typedef __attribute__((ext_vector_type(8))) short short8;
typedef __attribute__((ext_vector_type(4))) float float4v;

struct us4 { unsigned short x, y, z, w; };
struct us8 { unsigned short v[8]; };

__device__ __forceinline__ unsigned short f2bf(float f) {
    unsigned u = __float_as_uint(f);
    unsigned r = (u + 0x7FFF + ((u >> 16) & 1)) >> 16;   // RNE
    return (unsigned short)r;
}

__device__ __forceinline__ float bf2f(unsigned short u) {
    return __uint_as_float((unsigned)u << 16);
}

__device__ __forceinline__ void gload_lds16(const unsigned short* g, unsigned short* l) {
    __builtin_amdgcn_global_load_lds(
        (const __attribute__((address_space(1))) unsigned int*)g,
        (__attribute__((address_space(3))) unsigned int*)l,
        16, 0, 0);
}

// ---------------- bf16 MFMA GEMM: C[N,M] = A[N,K] @ Bt[M,K]^T ----------------
// A row-major bf16 [N,K]; Bt row-major bf16 [M,K]. global_load_lds staging only
// (VGPR->LDS b128 staging measured 3.2M bank conflicts -- do not reintroduce).
template <int BM, int BN, int WM, int WN, int OUTBF>
__global__ __launch_bounds__(256) void gemm_mfma(const unsigned short* __restrict__ A,
                                                 const unsigned short* __restrict__ Bt,
                                                 void* __restrict__ Cv,
                                                 int N, int K, int M) {
    constexpr int BK = 32;
    constexpr int MT = WM / 16;
    constexpr int NT = WN / 16;
    constexpr int WCOLS = BN / WN;

    __shared__ __align__(16) unsigned short As[BM * BK];
    __shared__ __align__(16) unsigned short Bs[BN * BK];

    const int tid = threadIdx.x;
    const int lane = tid & 63;
    const int wid = tid >> 6;
    const int col16 = lane & 15;
    const int q = lane >> 4;
    const int wr = (wid / WCOLS) * WM;
    const int wc = (wid % WCOLS) * WN;
    const int rowBase = blockIdx.y * BM;
    const int colBase = blockIdx.x * BN;

    const int srow = lane >> 2;
    const int scol = (lane & 3) * 8;

    float4v acc[MT][NT];
#pragma unroll
    for (int t = 0; t < MT; ++t)
#pragma unroll
        for (int u = 0; u < NT; ++u)
            acc[t][u] = (float4v)0.f;

    for (int k0 = 0; k0 < K; k0 += BK) {
        __syncthreads();
#pragma unroll
        for (int l = wid; l < BM / 16; l += 4) {
            int row = rowBase + 16 * l + srow;
            row = row < N ? row : N - 1;
            gload_lds16(A + (size_t)row * K + k0 + scol, &As[l * 512]);
        }
#pragma unroll
        for (int l = wid; l < BN / 16; l += 4) {
            const int row = colBase + 16 * l + srow;
            gload_lds16(Bt + (size_t)row * K + k0 + scol, &Bs[l * 512]);
        }
        __syncthreads();

        short8 a[MT], b[NT];
#pragma unroll
        for (int t = 0; t < MT; ++t)
            a[t] = *(const short8*)&As[(wr + t * 16 + col16) * BK + q * 8];
#pragma unroll
        for (int u = 0; u < NT; ++u)
            b[u] = *(const short8*)&Bs[(wc + u * 16 + col16) * BK + q * 8];
#pragma unroll
        for (int t = 0; t < MT; ++t)
#pragma unroll
            for (int u = 0; u < NT; ++u)
                acc[t][u] = __builtin_amdgcn_mfma_f32_16x16x32_bf16(a[t], b[u], acc[t][u], 0, 0, 0);
    }

    // epilogue: C/D layout col=lane&15, row=q*4+reg
#pragma unroll
    for (int t = 0; t < MT; ++t) {
        const int row0 = rowBase + wr + t * 16 + q * 4;
#pragma unroll
        for (int u = 0; u < NT; ++u) {
            const int col = colBase + wc + u * 16 + col16;
#pragma unroll
            for (int r = 0; r < 4; ++r) {
                const int row = row0 + r;
                if (row < N) {
                    if (OUTBF)
                        ((unsigned short*)Cv)[(size_t)row * M + col] = f2bf(acc[t][u][r]);
                    else
                        ((float*)Cv)[(size_t)row * M + col] = acc[t][u][r];
                }
            }
        }
    }
}

// ---------------- conversions ----------------
__global__ void cvt_f32_bf16(const float* __restrict__ in, unsigned short* __restrict__ out,
                             long long n4) {
    long long i = (long long)blockIdx.x * blockDim.x + threadIdx.x;
    const long long stride = (long long)gridDim.x * blockDim.x;
    for (; i < n4; i += stride) {
        const float4 v = *(const float4*)&in[i * 4];
        us4 o = {f2bf(v.x), f2bf(v.y), f2bf(v.z), f2bf(v.w)};
        *(us4*)&out[i * 4] = o;
    }
}

// all four W -> Wt transposes in one launch
__global__ void cvt_transpose_all(const float* __restrict__ W1, unsigned short* __restrict__ Wt1,
                                  const float* __restrict__ W2, unsigned short* __restrict__ Wt2,
                                  const float* __restrict__ W3, unsigned short* __restrict__ Wt3,
                                  const float* __restrict__ W4, unsigned short* __restrict__ Wt4) {
    int idx = blockIdx.x * blockDim.x + threadIdx.x;
    const float* W; unsigned short* Wt; int K, M;
    if (idx < 262144)      { W = W1; Wt = Wt1; K = 512; M = 512; }
    else if (idx < 393216) { idx -= 262144; W = W2; Wt = Wt2; K = 512; M = 256; }
    else if (idx < 425984) { idx -= 393216; W = W3; Wt = Wt3; K = 256; M = 128; }
    else if (idx < 434176) { idx -= 425984; W = W4; Wt = Wt4; K = 128; M = 64; }
    else return;
    const int k = idx / M;
    const int m = idx % M;
    Wt[(size_t)m * K + k] = f2bf(W[(size_t)k * M + m]);
}

// ---------------- CSR build ----------------
__global__ void zero_counts(int* __restrict__ counts) {
    int i = blockIdx.x * blockDim.x + threadIdx.x;
    if (i < NN) counts[i] = 0;
}

__global__ void hist_dst(const int* __restrict__ dst, int* __restrict__ counts) {
    int i = blockIdx.x * blockDim.x + threadIdx.x;
    const int stride = gridDim.x * blockDim.x;
    for (; i < NE; i += stride) atomicAdd(&counts[dst[i]], 1);
}

__global__ __launch_bounds__(256) void scan_partial(const int* __restrict__ counts,
                                                    int* __restrict__ partials) {
    __shared__ int r[256];
    const int t = threadIdx.x;
    const int i = blockIdx.x * 256 + t;
    r[t] = (i < NN) ? counts[i] : 0;
    __syncthreads();
    for (int s = 128; s > 0; s >>= 1) {
        if (t < s) r[t] += r[t + s];
        __syncthreads();
    }
    if (t == 0) partials[blockIdx.x] = r[0];
}

__global__ __launch_bounds__(256) void scan_base(const int* __restrict__ partials,
                                                 int* __restrict__ bases,
                                                 int* __restrict__ offs) {
    __shared__ int s[256];
    const int t = threadIdx.x;
    const int v = (t < SCAN_BLOCKS) ? partials[t] : 0;
    s[t] = v;
    __syncthreads();
    for (int off = 1; off < 256; off <<= 1) {
        int x = (t >= off) ? s[t - off] : 0;
        __syncthreads();
        s[t] += x;
        __syncthreads();
    }
    if (t < SCAN_BLOCKS) bases[t] = s[t] - v;
    if (t == 255) offs[NN] = s[255];
}

__global__ __launch_bounds__(256) void scan_final(int* __restrict__ counts,
                                                  const int* __restrict__ bases,
                                                  int* __restrict__ offs) {
    __shared__ int s[256];
    const int t = threadIdx.x;
    const int i = blockIdx.x * 256 + t;
    const int v = (i < NN) ? counts[i] : 0;
    s[t] = v;
    __syncthreads();
    for (int off = 1; off < 256; off <<= 1) {
        int x = (t >= off) ? s[t - off] : 0;
        __syncthreads();
        s[t] += x;
        __syncthreads();
    }
    if (i < NN) {
        const int e = bases[blockIdx.x] + s[t] - v;
        offs[i] = e;
        counts[i] = e;
    }
}

__global__ void fill_csr(const int* __restrict__ src, const int* __restrict__ dst,
                         const float* __restrict__ w, int* __restrict__ cursor,
                         int* __restrict__ csr_src, float* __restrict__ csr_w) {
    int i = blockIdx.x * blockDim.x + threadIdx.x;
    const int stride = gridDim.x * blockDim.x;
    for (; i < NE; i += stride) {
        const int p = atomicAdd(&cursor[dst[i]], 1);
        csr_src[p] = src[i];
        csr_w[p] = w[i];
    }
}

// ---------------- gather SpMM (bf16 h input), 4x edge unroll ----------------
// Computes columns [dbase, dbase+D) of the output; h/out row stride = dstride.
template <int D, int RELU, int OUTBF>
__global__ __launch_bounds__(256) void spmm_gather(const int* __restrict__ offs,
                                                   const int* __restrict__ csr_src,
                                                   const float* __restrict__ csr_w,
                                                   const unsigned short* __restrict__ hp,
                                                   const float* __restrict__ bias,
                                                   void* __restrict__ outv,
                                                   int dbase, int dstride) {
    constexpr int TPN = D / 8;
    constexpr int NPB = 256 / TPN;
    const int tid = threadIdx.x;
    const int node = blockIdx.x * NPB + tid / TPN;
    const int d = dbase + (tid % TPN) * 8;
    if (node >= NN) return;
    const int beg = offs[node];
    const int end = offs[node + 1];

    float acc[8] = {};
    int j = beg;
    for (; j + 4 <= end; j += 4) {
        const int s0 = csr_src[j];
        const int s1 = csr_src[j + 1];
        const int s2 = csr_src[j + 2];
        const int s3 = csr_src[j + 3];
        const float w0 = csr_w[j];
        const float w1 = csr_w[j + 1];
        const float w2 = csr_w[j + 2];
        const float w3 = csr_w[j + 3];
        const us8 h0 = *(const us8*)&hp[(long long)s0 * dstride + d];
        const us8 h1 = *(const us8*)&hp[(long long)s1 * dstride + d];
        const us8 h2 = *(const us8*)&hp[(long long)s2 * dstride + d];
        const us8 h3 = *(const us8*)&hp[(long long)s3 * dstride + d];
#pragma unroll
        for (int k = 0; k < 8; ++k)
            acc[k] += w0 * bf2f(h0.v[k]) + w1 * bf2f(h1.v[k])
                    + w2 * bf2f(h2.v[k]) + w3 * bf2f(h3.v[k]);
    }
    for (; j < end; ++j) {
        const int s0 = csr_src[j];
        const float w0 = csr_w[j];
        const us8 h0 = *(const us8*)&hp[(long long)s0 * dstride + d];
#pragma unroll
        for (int k = 0; k < 8; ++k)
            acc[k] += w0 * bf2f(h0.v[k]);
    }
#pragma unroll
    for (int k = 0; k < 8; ++k) {
        acc[k] += bias[d + k];
        if (RELU) acc[k] = fmaxf(acc[k], 0.f);
    }
    if (OUTBF) {
        us8 o;
#pragma unroll
        for (int k = 0; k < 8; ++k) o.v[k] = f2bf(acc[k]);
        *(us8*)((unsigned short*)outv + (long long)node * dstride + d) = o;
    } else {
        float* op = (float*)outv + (long long)node * dstride + d;
        *(float4*)op = make_float4(acc[0], acc[1], acc[2], acc[3]);
        *(float4*)(op + 4) = make_float4(acc[4], acc[5], acc[6], acc[7]);
    }
}

extern "C" void kernel_launch(void* const* d_in, const int* in_sizes, int n_in,
                              void* d_out, int out_size, void* d_ws, size_t ws_size,
                              hipStream_t stream) {
    const float* x    = (const float*)d_in[0];
    const int*   esrc = (const int*)d_in[1];
    const int*   edst = (const int*)d_in[2];
    const float* ew   = (const float*)d_in[3];
    const float* W1 = (const float*)d_in[4];  const float* b1 = (const float*)d_in[5];
    const float* W2 = (const float*)d_in[6];  const float* b2 = (const float*)d_in[7];
    const float* W3 = (const float*)d_in[8];  const float* b3 = (const float*)d_in[9];
    const float* W4 = (const float*)d_in[10]; const float* b4 = (const float*)d_in[11];
    float* out = (float*)d_out;

    // workspace layout (~115 MB)
    char* ws = (char*)d_ws;
    int*   offs    = (int*)ws;                    ws += (NN + 1) * sizeof(int);
    int*   counts  = (int*)ws;                    ws += NN * sizeof(int);
    int*   partials= (int*)ws;                    ws += 256 * sizeof(int);
    int*   bases   = (int*)ws;                    ws += 256 * sizeof(int);
    int*   csr_src = (int*)ws;                    ws += NE * sizeof(int);
    float* csr_w   = (float*)ws;                  ws += NE * sizeof(float);
    unsigned short* Wt1 = (unsigned short*)ws;    ws += 512 * 512 * sizeof(unsigned short);
    unsigned short* Wt2 = (unsigned short*)ws;    ws += 256 * 512 * sizeof(unsigned short);
    unsigned short* Wt3 = (unsigned short*)ws;    ws += 128 * 256 * sizeof(unsigned short);
    unsigned short* Wt4 = (unsigned short*)ws;    ws += 64 * 128 * sizeof(unsigned short);
    ws = (char*)(((uintptr_t)ws + 255) & ~(uintptr_t)255);
    unsigned short* tmp = (unsigned short*)ws;    ws += (size_t)NN * 512 * sizeof(unsigned short);
    ws = (char*)(((uintptr_t)ws + 255) & ~(uintptr_t)255);
    unsigned short* hb = (unsigned short*)ws;     // N x 512 bf16; x, then h1..h3

    // ---- CSR build ----
    zero_counts<<<(NN + 255) / 256, 256, 0, stream>>>(counts);
    hist_dst<<<3125, 256, 0, stream>>>(edst, counts);
    scan_partial<<<SCAN_BLOCKS, 256, 0, stream>>>(counts, partials);
    scan_base<<<1, 256, 0, stream>>>(partials, bases, offs);
    scan_final<<<SCAN_BLOCKS, 256, 0, stream>>>(counts, bases, offs);
    fill_csr<<<3125, 256, 0, stream>>>(esrc, edst, ew, counts, csr_src, csr_w);

    // ---- conversions ----
    cvt_f32_bf16<<<12800, 256, 0, stream>>>(x, hb, (long long)NN * 512 / 4);
    cvt_transpose_all<<<(434176 + 255) / 256, 256, 0, stream>>>(W1, Wt1, W2, Wt2, W3, Wt3, W4, Wt4);

    const int nby128 = (NN + 127) / 128;   // 391
    const int nby64  = (NN + 63) / 64;     // 782

    // ---- layer 1: K=512, M=512 ----
    gemm_mfma<128, 128, 64, 64, 1><<<dim3(4, nby128), 256, 0, stream>>>(hb, Wt1, tmp, NN, 512, 512);
    // gather split into two 256-column passes (h footprint 25.6 MB/pass vs 32 MB L2)
    spmm_gather<256, 1, 1><<<NN / 8, 256, 0, stream>>>(offs, csr_src, csr_w, tmp, b1, hb, 0, 512);
    spmm_gather<256, 1, 1><<<NN / 8, 256, 0, stream>>>(offs, csr_src, csr_w, tmp, b1, hb, 256, 512);
    // ---- layer 2: K=512, M=256 ----
    gemm_mfma<128, 128, 64, 64, 1><<<dim3(2, nby128), 256, 0, stream>>>(hb, Wt2, tmp, NN, 512, 256);
    spmm_gather<256, 1, 1><<<NN / 8, 256, 0, stream>>>(offs, csr_src, csr_w, tmp, b2, hb, 0, 256);
    // ---- layer 3: K=256, M=128 ----
    gemm_mfma<64, 128, 32, 64, 1><<<dim3(1, nby64), 256, 0, stream>>>(hb, Wt3, tmp, NN, 256, 128);
    spmm_gather<128, 1, 1><<<NN / 16, 256, 0, stream>>>(offs, csr_src, csr_w, tmp, b3, hb, 0, 128);
    // ---- layer 4: K=128, M=64 ----
    gemm_mfma<64, 64, 32, 32, 1><<<dim3(1, nby64), 256, 0, stream>>>(hb, Wt4, tmp, NN, 128, 64);
    spmm_gather<64, 0, 0><<<(NN + 31) / 32, 256, 0, stream>>>(offs, csr_src, csr_w, tmp, b4, out, 0, 64);
}